// Round 1
// baseline (2474.791 us; speedup 1.0000x reference)
//
#include <hip/hip_runtime.h>
#include <math.h>

#define B_  4
#define T_  2048
#define D_  1024
#define H_  16
#define HD_ 64
#define SCALE 0.125f   // HD^-0.5

// ---------------------------------------------------------------------------
// Kernel 1: fused QKV projection.
// C[M=8192, N=3*16*64] = X[8192,1024] * W + b, written directly into
// q/k/v buffers laid out [B,H,T,HD].
// Tiling: BM=128, BN=64 (= exactly one head's e-range), BK=32, 256 thr, 8x4.
// ---------------------------------------------------------------------------
__global__ __launch_bounds__(256) void qkv_kernel(
    const float* __restrict__ x,
    const float* __restrict__ Wq, const float* __restrict__ bq,
    const float* __restrict__ Wk, const float* __restrict__ bk,
    const float* __restrict__ Wv, const float* __restrict__ bv,
    float* __restrict__ qkv)           // [3][B,H,T,HD]
{
    const int tid = threadIdx.x;
    const int nb  = blockIdx.y;        // 0..47
    const int sel = nb >> 4;           // 0=q 1=k 2=v
    const int h   = nb & 15;

    const float* W;  const float* bias;
    if      (sel == 0) { W = Wq; bias = bq; }
    else if (sel == 1) { W = Wk; bias = bk; }
    else               { W = Wv; bias = bv; }
    W    += (size_t)h * D_ * HD_;      // [D, HD] for this head
    bias += h * HD_;

    const int m0 = blockIdx.x * 128;   // global row (b*T + t)
    const int b  = m0 >> 11;           // T_=2048
    const int t0 = m0 & (T_ - 1);
    float* out = qkv + (((size_t)sel * B_ * H_) + (size_t)b * H_ + h) * T_ * HD_;

    __shared__ float As[32][132];      // As[k][m], stride 132 (4-aligned, conflict-light)
    __shared__ float Bs[32][68];       // Bs[k][n]

    const int rg = tid >> 4, cg = tid & 15;
    const int r0 = rg * 8,  c0 = cg * 4;

    float acc[8][4];
    #pragma unroll
    for (int i = 0; i < 8; ++i)
        #pragma unroll
        for (int j = 0; j < 4; ++j) acc[i][j] = 0.f;

    for (int k0 = 0; k0 < D_; k0 += 32) {
        // stage A transposed: X[m0+m][k0+k] -> As[k][m]
        {
            const int k = tid & 31, mb = tid >> 5;   // 8 rows/pass
            #pragma unroll
            for (int p = 0; p < 16; ++p) {
                int m = mb + p * 8;
                As[k][m] = x[(size_t)(m0 + m) * D_ + k0 + k];
            }
        }
        // stage B direct: W[k0+k][n] -> Bs[k][n]
        {
            const int n = tid & 63, kb = tid >> 6;
            #pragma unroll
            for (int p = 0; p < 8; ++p) {
                int k = kb + p * 4;
                Bs[k][n] = W[(size_t)(k0 + k) * HD_ + n];
            }
        }
        __syncthreads();
        #pragma unroll
        for (int k = 0; k < 32; ++k) {
            float a0[4], a1[4], bb[4];
            *(float4*)a0 = *(const float4*)&As[k][r0];
            *(float4*)a1 = *(const float4*)&As[k][r0 + 4];
            *(float4*)bb = *(const float4*)&Bs[k][c0];
            #pragma unroll
            for (int i = 0; i < 4; ++i)
                #pragma unroll
                for (int j = 0; j < 4; ++j) {
                    acc[i][j]     = fmaf(a0[i], bb[j], acc[i][j]);
                    acc[i + 4][j] = fmaf(a1[i], bb[j], acc[i + 4][j]);
                }
        }
        __syncthreads();
    }

    float4 bv4 = *(const float4*)&bias[c0];
    #pragma unroll
    for (int i = 0; i < 8; ++i) {
        int t = t0 + r0 + i;
        float4 o;
        o.x = acc[i][0] + bv4.x;  o.y = acc[i][1] + bv4.y;
        o.z = acc[i][2] + bv4.z;  o.w = acc[i][3] + bv4.w;
        *(float4*)&out[(size_t)t * HD_ + c0] = o;
    }
}

// ---------------------------------------------------------------------------
// Kernel 2: causal flash attention, fp32. One block = one (b,h,64-row q-tile).
// 256 threads = 16x16 grid of 4x4 micro-tiles. Online softmax kept fully in
// registers (m/l replicated across the 16 lanes of each row-group).
// ---------------------------------------------------------------------------
__global__ __launch_bounds__(256) void attn_kernel(
    const float* __restrict__ qkv, float* __restrict__ att)   // att: [B,T,D]
{
    const int tid = threadIdx.x;
    const int by  = blockIdx.y;                 // b*H + h
    const int h   = by & (H_ - 1);
    const int b   = by >> 4;
    const int qt  = gridDim.x - 1 - blockIdx.x; // heavy tiles first
    const int q0  = qt * 64;

    const size_t bh = (size_t)by * T_ * HD_;
    const size_t PL = (size_t)B_ * H_ * T_ * HD_;
    const float* Q = qkv + bh;
    const float* K = qkv + PL + bh;
    const float* V = qkv + 2 * PL + bh;

    __shared__ float QT[64][68];   // QT[e][r]
    __shared__ float KT[64][68];   // KT[e][c]
    __shared__ float PT[64][68];   // PT[c][r]
    __shared__ float Vs[64][64];   // Vs[c][e]

    const int rg = tid >> 4, cg = tid & 15;
    const int r0 = rg * 4,  c0 = cg * 4;

    // load Q tile (transposed into LDS), float4 global reads
    #pragma unroll
    for (int p = 0; p < 4; ++p) {
        int flat = p * 256 + tid;          // 1024 float4s
        int r = flat >> 4, e0 = (flat & 15) * 4;
        float4 qv = *(const float4*)&Q[(size_t)(q0 + r) * HD_ + e0];
        QT[e0 + 0][r] = qv.x; QT[e0 + 1][r] = qv.y;
        QT[e0 + 2][r] = qv.z; QT[e0 + 3][r] = qv.w;
    }

    float o[4][4];
    #pragma unroll
    for (int i = 0; i < 4; ++i)
        #pragma unroll
        for (int j = 0; j < 4; ++j) o[i][j] = 0.f;
    float mreg[4], lreg[4];
    #pragma unroll
    for (int i = 0; i < 4; ++i) { mreg[i] = -INFINITY; lreg[i] = 0.f; }

    for (int j0 = 0; j0 <= q0; j0 += 64) {
        __syncthreads();   // prev iter done reading KT/Vs/PT
        #pragma unroll
        for (int p = 0; p < 4; ++p) {
            int flat = p * 256 + tid;
            int c = flat >> 4, e0 = (flat & 15) * 4;
            float4 kv = *(const float4*)&K[(size_t)(j0 + c) * HD_ + e0];
            KT[e0 + 0][c] = kv.x; KT[e0 + 1][c] = kv.y;
            KT[e0 + 2][c] = kv.z; KT[e0 + 3][c] = kv.w;
            float4 vv = *(const float4*)&V[(size_t)(j0 + c) * HD_ + e0];
            *(float4*)&Vs[c][e0] = vv;
        }
        __syncthreads();

        // S = Q K^T  (outer-product over e)
        float s[4][4];
        #pragma unroll
        for (int i = 0; i < 4; ++i)
            #pragma unroll
            for (int j = 0; j < 4; ++j) s[i][j] = 0.f;
        #pragma unroll
        for (int e = 0; e < 64; ++e) {
            float4 a  = *(const float4*)&QT[e][r0];
            float4 bb = *(const float4*)&KT[e][c0];
            const float av[4] = {a.x, a.y, a.z, a.w};
            const float bw[4] = {bb.x, bb.y, bb.z, bb.w};
            #pragma unroll
            for (int i = 0; i < 4; ++i)
                #pragma unroll
                for (int j = 0; j < 4; ++j)
                    s[i][j] = fmaf(av[i], bw[j], s[i][j]);
        }

        const bool diag = (j0 == q0);
        #pragma unroll
        for (int i = 0; i < 4; ++i)
            #pragma unroll
            for (int j = 0; j < 4; ++j) {
                s[i][j] *= SCALE;
                if (diag && (c0 + j) > (r0 + i)) s[i][j] = -INFINITY;
            }

        // online softmax, per row-group (16 lanes share a row via shfl_xor)
        float p_[4][4];
        #pragma unroll
        for (int i = 0; i < 4; ++i) {
            float pm = fmaxf(fmaxf(s[i][0], s[i][1]), fmaxf(s[i][2], s[i][3]));
            #pragma unroll
            for (int d = 1; d < 16; d <<= 1) pm = fmaxf(pm, __shfl_xor(pm, d));
            float mnew = fmaxf(mreg[i], pm);
            float fac  = __expf(mreg[i] - mnew);   // exp(-inf)=0 on first tile
            float sum  = 0.f;
            #pragma unroll
            for (int j = 0; j < 4; ++j) {
                p_[i][j] = __expf(s[i][j] - mnew);
                sum += p_[i][j];
            }
            #pragma unroll
            for (int d = 1; d < 16; d <<= 1) sum += __shfl_xor(sum, d);
            lreg[i] = lreg[i] * fac + sum;
            mreg[i] = mnew;
            #pragma unroll
            for (int j = 0; j < 4; ++j) o[i][j] *= fac;
        }

        // PT[c][r] = P[r][c]
        #pragma unroll
        for (int i = 0; i < 4; ++i)
            #pragma unroll
            for (int j = 0; j < 4; ++j) PT[c0 + j][r0 + i] = p_[i][j];
        __syncthreads();

        // O += P V  (outer-product over c)
        #pragma unroll
        for (int c = 0; c < 64; ++c) {
            float4 a  = *(const float4*)&PT[c][r0];
            float4 bb = *(const float4*)&Vs[c][c0];
            const float av[4] = {a.x, a.y, a.z, a.w};
            const float bw[4] = {bb.x, bb.y, bb.z, bb.w};
            #pragma unroll
            for (int i = 0; i < 4; ++i)
                #pragma unroll
                for (int j = 0; j < 4; ++j)
                    o[i][j] = fmaf(av[i], bw[j], o[i][j]);
        }
    }

    // epilogue: normalize, write att[b, q0+r, h*64+e]
    float* outp = att + ((size_t)b * T_ + q0) * D_ + h * HD_;
    #pragma unroll
    for (int i = 0; i < 4; ++i) {
        float inv = 1.0f / lreg[i];
        float4 ov;
        ov.x = o[i][0] * inv; ov.y = o[i][1] * inv;
        ov.z = o[i][2] * inv; ov.w = o[i][3] * inv;
        *(float4*)&outp[(size_t)(r0 + i) * D_ + c0] = ov;
    }
}

// ---------------------------------------------------------------------------
// Kernel 3: output projection. out[m][n] = sum_k y[m][k]*Wp[n][k] + bp[n].
// Same tiling as kernel 1; B operand transposed during staging.
// ---------------------------------------------------------------------------
__global__ __launch_bounds__(256) void proj_kernel(
    const float* __restrict__ y, const float* __restrict__ Wp,
    const float* __restrict__ bp, float* __restrict__ out)
{
    const int tid = threadIdx.x;
    const int m0 = blockIdx.x * 128;
    const int n0 = blockIdx.y * 64;

    __shared__ float As[32][132];
    __shared__ float Bs[32][68];

    const int rg = tid >> 4, cg = tid & 15;
    const int r0 = rg * 8,  c0 = cg * 4;

    float acc[8][4];
    #pragma unroll
    for (int i = 0; i < 8; ++i)
        #pragma unroll
        for (int j = 0; j < 4; ++j) acc[i][j] = 0.f;

    for (int k0 = 0; k0 < D_; k0 += 32) {
        {
            const int k = tid & 31, mb = tid >> 5;
            #pragma unroll
            for (int p = 0; p < 16; ++p) {
                int m = mb + p * 8;
                As[k][m] = y[(size_t)(m0 + m) * D_ + k0 + k];
            }
        }
        {   // Bs[k][n] = Wp[n0+n][k0+k]  (transpose during stage)
            const int k = tid & 31, nb = tid >> 5;
            #pragma unroll
            for (int p = 0; p < 8; ++p) {
                int n = nb + p * 8;
                Bs[k][n] = Wp[(size_t)(n0 + n) * D_ + k0 + k];
            }
        }
        __syncthreads();
        #pragma unroll
        for (int k = 0; k < 32; ++k) {
            float a0[4], a1[4], bb[4];
            *(float4*)a0 = *(const float4*)&As[k][r0];
            *(float4*)a1 = *(const float4*)&As[k][r0 + 4];
            *(float4*)bb = *(const float4*)&Bs[k][c0];
            #pragma unroll
            for (int i = 0; i < 4; ++i)
                #pragma unroll
                for (int j = 0; j < 4; ++j) {
                    acc[i][j]     = fmaf(a0[i], bb[j], acc[i][j]);
                    acc[i + 4][j] = fmaf(a1[i], bb[j], acc[i + 4][j]);
                }
        }
        __syncthreads();
    }

    float4 bv4 = *(const float4*)&bp[n0 + c0];
    #pragma unroll
    for (int i = 0; i < 8; ++i) {
        float4 ov;
        ov.x = acc[i][0] + bv4.x;  ov.y = acc[i][1] + bv4.y;
        ov.z = acc[i][2] + bv4.z;  ov.w = acc[i][3] + bv4.w;
        *(float4*)&out[(size_t)(m0 + r0 + i) * D_ + n0 + c0] = ov;
    }
}

// ---------------------------------------------------------------------------
extern "C" void kernel_launch(void* const* d_in, const int* in_sizes, int n_in,
                              void* d_out, int out_size, void* d_ws, size_t ws_size,
                              hipStream_t stream) {
    (void)in_sizes; (void)n_in; (void)out_size; (void)ws_size;
    const float* x  = (const float*)d_in[0];
    const float* Wq = (const float*)d_in[1];
    const float* bq = (const float*)d_in[2];
    const float* Wk = (const float*)d_in[3];
    const float* bk = (const float*)d_in[4];
    const float* Wv = (const float*)d_in[5];
    const float* bv = (const float*)d_in[6];
    const float* Wp = (const float*)d_in[7];
    const float* bp = (const float*)d_in[8];
    float* out = (float*)d_out;
    float* ws  = (float*)d_ws;

    float* qkv = ws;                                     // 3*B*H*T*HD floats (100.7 MB)
    float* att = ws + (size_t)3 * B_ * H_ * T_ * HD_;    // B*T*D floats (33.6 MB)

    qkv_kernel<<<dim3(64, 48), 256, 0, stream>>>(x, Wq, bq, Wk, bk, Wv, bv, qkv);
    attn_kernel<<<dim3(T_ / 64, B_ * H_), 256, 0, stream>>>(qkv, att);
    proj_kernel<<<dim3(64, 16), 256, 0, stream>>>(att, Wp, bp, out);
}

// Round 2
// 494.009 us; speedup vs baseline: 5.0096x; 5.0096x over previous
//
#include <hip/hip_runtime.h>
#include <math.h>

#define B_  4
#define T_  2048
#define D_  1024
#define H_  16
#define HD_ 64
#define SCALE 0.125f
#define LSTR 72   // LDS inner stride (bf16 units): 144B = 16B-aligned, conflict-free for MFMA frag reads

typedef __attribute__((ext_vector_type(8))) short  s8v;   // 8 bf16 = one MFMA A/B frag (4 VGPR)
typedef __attribute__((ext_vector_type(4))) float  f4v;   // MFMA C/D frag
typedef __attribute__((ext_vector_type(8))) unsigned short u8v;
typedef __attribute__((ext_vector_type(4))) unsigned short u4v;
typedef __attribute__((ext_vector_type(2))) unsigned short u2v;

static __device__ __forceinline__ unsigned short f2b(float f) {
    unsigned u = __builtin_bit_cast(unsigned, f);
    u = (u + 0x7fffu + ((u >> 16) & 1u)) >> 16;   // RNE
    return (unsigned short)u;
}
static __device__ __forceinline__ f4v mfma16(s8v a, s8v b, f4v c) {
    return __builtin_amdgcn_mfma_f32_16x16x32_bf16(a, b, c, 0, 0, 0);
}

// ---------------------------------------------------------------------------
// Prep 1: straight fp32 -> bf16 convert (x, Wp)
// ---------------------------------------------------------------------------
__global__ void cvt_f2b_kernel(const float* __restrict__ src,
                               unsigned short* __restrict__ dst, int n4) {
    int i = blockIdx.x * blockDim.x + threadIdx.x;
    int stride = gridDim.x * blockDim.x;
    for (; i < n4; i += stride) {
        float4 v = reinterpret_cast<const float4*>(src)[i];
        u4v o;
        o[0] = f2b(v.x); o[1] = f2b(v.y); o[2] = f2b(v.z); o[3] = f2b(v.w);
        reinterpret_cast<u4v*>(dst)[i] = o;
    }
}

// ---------------------------------------------------------------------------
// Prep 2: Wq/Wk/Wv [sel][h][k(1024)][e(64)] fp32 -> Wb [sel*16+h][e(64)][k(1024)] bf16
// (transpose so GEMM B-operand staging is contiguous in k)
// ---------------------------------------------------------------------------
__global__ __launch_bounds__(256) void cvt_wqkv(
    const float* __restrict__ Wq, const float* __restrict__ Wk,
    const float* __restrict__ Wv, unsigned short* __restrict__ Wb) {
    const int tid = threadIdx.x;
    const int kblk = blockIdx.x;          // 0..7  (1024/128)
    const int by = blockIdx.y;            // sel*16+h, 0..47
    const int sel = by >> 4, h = by & 15;
    const float* W = (sel == 0 ? Wq : sel == 1 ? Wk : Wv) + (size_t)h * D_ * HD_ + (size_t)kblk * 128 * HD_;

    __shared__ unsigned short L[128 * 68];   // [k-row][e]

    #pragma unroll
    for (int p = 0; p < 8; ++p) {
        int flat = p * 256 + tid;
        int r = flat >> 4, e4 = (flat & 15) * 4;
        float4 v = *(const float4*)&W[(size_t)r * HD_ + e4];
        L[r * 68 + e4 + 0] = f2b(v.x);
        L[r * 68 + e4 + 1] = f2b(v.y);
        L[r * 68 + e4 + 2] = f2b(v.z);
        L[r * 68 + e4 + 3] = f2b(v.w);
    }
    __syncthreads();
    #pragma unroll
    for (int p = 0; p < 8; ++p) {
        int flat = p * 256 + tid;
        int e = flat >> 5, rc = (flat & 31) * 4;
        u4v o;
        o[0] = L[(rc + 0) * 68 + e];
        o[1] = L[(rc + 1) * 68 + e];
        o[2] = L[(rc + 2) * 68 + e];
        o[3] = L[(rc + 3) * 68 + e];
        *(u4v*)&Wb[((size_t)by * HD_ + e) * D_ + kblk * 128 + rc] = o;
    }
}

// ---------------------------------------------------------------------------
// Kernel 1: fused QKV projection, bf16 MFMA. BM=128, BN=64 (one (sel,h)),
// BK=64. 4 waves: wave tile 64x32 (4 m-frags x 2 n-frags).
// ---------------------------------------------------------------------------
__global__ __launch_bounds__(256) void qkv_mm(
    const unsigned short* __restrict__ xb, const unsigned short* __restrict__ Wb,
    const float* __restrict__ bq, const float* __restrict__ bk_,
    const float* __restrict__ bv, unsigned short* __restrict__ qkvb) {
    const int tid = threadIdx.x;
    const int m0 = blockIdx.x * 128;
    const int by = blockIdx.y;            // sel*16+h
    const int sel = by >> 4, h = by & 15;
    const float* bias = (sel == 0 ? bq : sel == 1 ? bk_ : bv) + h * HD_;
    const unsigned short* Wt = Wb + (size_t)by * HD_ * D_;

    __shared__ __align__(16) unsigned short As[128 * LSTR];
    __shared__ __align__(16) unsigned short Bs[64 * LSTR];

    const int w = tid >> 6, lane = tid & 63;
    const int el = lane & 15, eh = lane >> 4;
    const int wm = w >> 1, wn = w & 1;

    f4v acc[4][2];
    #pragma unroll
    for (int i = 0; i < 4; ++i)
        #pragma unroll
        for (int j = 0; j < 2; ++j) acc[i][j] = 0.f;

    for (int k0 = 0; k0 < D_; k0 += 64) {
        #pragma unroll
        for (int p = 0; p < 4; ++p) {
            int flat = p * 256 + tid;
            int row = flat >> 3, kc = (flat & 7) * 8;
            *(u8v*)&As[row * LSTR + kc] = *(const u8v*)&xb[(size_t)(m0 + row) * D_ + k0 + kc];
        }
        #pragma unroll
        for (int p = 0; p < 2; ++p) {
            int flat = p * 256 + tid;
            int n = flat >> 3, kc = (flat & 7) * 8;
            *(u8v*)&Bs[n * LSTR + kc] = *(const u8v*)&Wt[(size_t)n * D_ + k0 + kc];
        }
        __syncthreads();
        s8v a[4][2], b[2][2];
        #pragma unroll
        for (int i = 0; i < 4; ++i)
            #pragma unroll
            for (int ks = 0; ks < 2; ++ks)
                a[i][ks] = *(const s8v*)&As[(64 * wm + 16 * i + el) * LSTR + ks * 32 + eh * 8];
        #pragma unroll
        for (int j = 0; j < 2; ++j)
            #pragma unroll
            for (int ks = 0; ks < 2; ++ks)
                b[j][ks] = *(const s8v*)&Bs[(32 * wn + 16 * j + el) * LSTR + ks * 32 + eh * 8];
        #pragma unroll
        for (int i = 0; i < 4; ++i)
            #pragma unroll
            for (int j = 0; j < 2; ++j)
                #pragma unroll
                for (int ks = 0; ks < 2; ++ks)
                    acc[i][j] = mfma16(a[i][ks], b[j][ks], acc[i][j]);
        __syncthreads();
    }
    #pragma unroll
    for (int i = 0; i < 4; ++i)
        #pragma unroll
        for (int j = 0; j < 2; ++j) {
            int e = 32 * wn + 16 * j + el;
            float bb = bias[e];
            #pragma unroll
            for (int r = 0; r < 4; ++r) {
                int m = m0 + 64 * wm + 16 * i + 4 * eh + r;
                int bidx = m >> 11, t = m & (T_ - 1);
                size_t o = (((size_t)sel * B_ + bidx) * H_ + h) * (size_t)T_ * HD_ + (size_t)t * HD_ + e;
                qkvb[o] = f2b(acc[i][j][r] + bb);
            }
        }
}

// ---------------------------------------------------------------------------
// Kernel 2: causal flash attention, bf16 MFMA. Block = (b,h, 64-row q-tile),
// 4 waves x 16 q-rows. Q lives in registers as A-frags; K/V^T in LDS;
// P transposed via per-wave LDS buffer. fp32 online softmax.
// ---------------------------------------------------------------------------
__global__ __launch_bounds__(256) void attn_mfma(
    const unsigned short* __restrict__ qkvb, unsigned short* __restrict__ attb) {
    const int tid = threadIdx.x;
    const int by = blockIdx.y;                  // b*H+h
    const int h = by & 15, b = by >> 4;
    const int qt = gridDim.x - 1 - blockIdx.x;  // heavy tiles first
    const int q0 = qt * 64;

    const size_t PL = (size_t)B_ * H_ * T_ * HD_;
    const unsigned short* Qp = qkvb + (size_t)by * T_ * HD_;
    const unsigned short* Kp = Qp + PL;
    const unsigned short* Vp = Qp + 2 * PL;

    const int w = tid >> 6, lane = tid & 63;
    const int el = lane & 15, eh = lane >> 4;
    const int qrbase = q0 + 16 * w;             // this wave's first q-row

    __shared__ __align__(16) unsigned short Ks[64 * LSTR];   // [kv][e]
    __shared__ __align__(16) unsigned short Vt[64 * LSTR];   // [e][kv]
    __shared__ __align__(16) unsigned short Pl[4][16 * LSTR];// per-wave [qrow][kv]

    // Q A-frags: row el, k-cols ks*32 + eh*8 .. +8   (held for whole kernel)
    s8v aq[2];
    #pragma unroll
    for (int ks = 0; ks < 2; ++ks)
        aq[ks] = *(const s8v*)&Qp[(size_t)(qrbase + el) * HD_ + ks * 32 + eh * 8];

    f4v o[4];
    #pragma unroll
    for (int j = 0; j < 4; ++j) o[j] = 0.f;
    float mrow[4], lrow[4];
    #pragma unroll
    for (int r = 0; r < 4; ++r) { mrow[r] = -INFINITY; lrow[r] = 0.f; }

    const int ntiles = qt + 1;
    for (int jt = 0; jt < ntiles; ++jt) {
        const int j0 = jt * 64;
        __syncthreads();   // previous tile's reads done
        // stage K [kv][e] (row-major, b128)
        #pragma unroll
        for (int p = 0; p < 2; ++p) {
            int flat = p * 256 + tid;
            int r = flat >> 3, kc = (flat & 7) * 8;
            *(u8v*)&Ks[r * LSTR + kc] = *(const u8v*)&Kp[(size_t)(j0 + r) * HD_ + kc];
        }
        // stage V transposed -> Vt[e][kv] via 2x2 dword transpose
        #pragma unroll
        for (int p = 0; p < 4; ++p) {
            int flat = p * 256 + tid;
            int kvp = flat >> 5, e2 = (flat & 31) * 2;
            u2v v0 = *(const u2v*)&Vp[(size_t)(j0 + 2 * kvp) * HD_ + e2];
            u2v v1 = *(const u2v*)&Vp[(size_t)(j0 + 2 * kvp + 1) * HD_ + e2];
            *(unsigned int*)&Vt[(e2 + 0) * LSTR + 2 * kvp] = (unsigned)v0[0] | ((unsigned)v1[0] << 16);
            *(unsigned int*)&Vt[(e2 + 1) * LSTR + 2 * kvp] = (unsigned)v0[1] | ((unsigned)v1[1] << 16);
        }
        __syncthreads();

        if (j0 <= qrbase + 15) {   // wave-uniform: any of my rows see this tile
            // S = Q K^T : 4 col-chunks x 2 k-steps
            f4v s[4];
            #pragma unroll
            for (int f = 0; f < 4; ++f) s[f] = 0.f;
            #pragma unroll
            for (int f = 0; f < 4; ++f)
                #pragma unroll
                for (int ks = 0; ks < 2; ++ks) {
                    s8v bk = *(const s8v*)&Ks[(16 * f + el) * LSTR + ks * 32 + eh * 8];
                    s[f] = mfma16(aq[ks], bk, s[f]);
                }
            // scale + causal mask   (D layout: row = 4*eh+r, col = 16*f+el)
            float sv[4][4];
            #pragma unroll
            for (int f = 0; f < 4; ++f)
                #pragma unroll
                for (int r = 0; r < 4; ++r) {
                    float x = s[f][r] * SCALE;
                    int row = qrbase + 4 * eh + r;
                    int col = j0 + 16 * f + el;
                    sv[f][r] = (col > row) ? -INFINITY : x;
                }
            // online softmax (row spread across 16 lanes: shfl_xor 1,2,4,8)
            float fac[4];
            #pragma unroll
            for (int r = 0; r < 4; ++r) {
                float pm = fmaxf(fmaxf(sv[0][r], sv[1][r]), fmaxf(sv[2][r], sv[3][r]));
                #pragma unroll
                for (int d = 1; d < 16; d <<= 1) pm = fmaxf(pm, __shfl_xor(pm, d));
                float mn = fmaxf(mrow[r], pm);
                fac[r] = __expf(mrow[r] - mn);
                mrow[r] = mn;
            }
            float rs[4] = {0.f, 0.f, 0.f, 0.f};
            #pragma unroll
            for (int f = 0; f < 4; ++f)
                #pragma unroll
                for (int r = 0; r < 4; ++r) {
                    float p = __expf(sv[f][r] - mrow[r]);
                    rs[r] += p;
                    Pl[w][(4 * eh + r) * LSTR + 16 * f + el] = f2b(p);
                }
            #pragma unroll
            for (int r = 0; r < 4; ++r) {
                #pragma unroll
                for (int d = 1; d < 16; d <<= 1) rs[r] += __shfl_xor(rs[r], d);
                lrow[r] = lrow[r] * fac[r] + rs[r];
            }
            #pragma unroll
            for (int j = 0; j < 4; ++j)
                #pragma unroll
                for (int r = 0; r < 4; ++r) o[j][r] *= fac[r];
            // O += P V : A-frags from Pl, B-frags from Vt
            s8v ap[2];
            #pragma unroll
            for (int ks = 0; ks < 2; ++ks)
                ap[ks] = *(const s8v*)&Pl[w][el * LSTR + ks * 32 + eh * 8];
            #pragma unroll
            for (int j = 0; j < 4; ++j)
                #pragma unroll
                for (int ks = 0; ks < 2; ++ks) {
                    s8v bv_ = *(const s8v*)&Vt[(16 * j + el) * LSTR + ks * 32 + eh * 8];
                    o[j] = mfma16(ap[ks], bv_, o[j]);
                }
        }
    }
    // epilogue: normalize, write bf16 att[b][t][h*64+e]
    float inv[4];
    #pragma unroll
    for (int r = 0; r < 4; ++r) inv[r] = 1.0f / lrow[r];
    #pragma unroll
    for (int j = 0; j < 4; ++j)
        #pragma unroll
        for (int r = 0; r < 4; ++r) {
            int row = b * T_ + qrbase + 4 * eh + r;
            int col = h * HD_ + 16 * j + el;
            attb[(size_t)row * D_ + col] = f2b(o[j][r] * inv[r]);
        }
}

// ---------------------------------------------------------------------------
// Kernel 3: output projection, bf16 MFMA. out[m][n] = sum_k att[m][k]*Wp[n][k] + bp[n]
// ---------------------------------------------------------------------------
__global__ __launch_bounds__(256) void proj_mm(
    const unsigned short* __restrict__ ab, const unsigned short* __restrict__ Wpb,
    const float* __restrict__ bp, float* __restrict__ out) {
    const int tid = threadIdx.x;
    const int m0 = blockIdx.x * 128;
    const int n0 = blockIdx.y * 64;

    __shared__ __align__(16) unsigned short As[128 * LSTR];
    __shared__ __align__(16) unsigned short Bs[64 * LSTR];

    const int w = tid >> 6, lane = tid & 63;
    const int el = lane & 15, eh = lane >> 4;
    const int wm = w >> 1, wn = w & 1;

    f4v acc[4][2];
    #pragma unroll
    for (int i = 0; i < 4; ++i)
        #pragma unroll
        for (int j = 0; j < 2; ++j) acc[i][j] = 0.f;

    for (int k0 = 0; k0 < D_; k0 += 64) {
        #pragma unroll
        for (int p = 0; p < 4; ++p) {
            int flat = p * 256 + tid;
            int row = flat >> 3, kc = (flat & 7) * 8;
            *(u8v*)&As[row * LSTR + kc] = *(const u8v*)&ab[(size_t)(m0 + row) * D_ + k0 + kc];
        }
        #pragma unroll
        for (int p = 0; p < 2; ++p) {
            int flat = p * 256 + tid;
            int n = flat >> 3, kc = (flat & 7) * 8;
            *(u8v*)&Bs[n * LSTR + kc] = *(const u8v*)&Wpb[(size_t)(n0 + n) * D_ + k0 + kc];
        }
        __syncthreads();
        s8v a[4][2], b[2][2];
        #pragma unroll
        for (int i = 0; i < 4; ++i)
            #pragma unroll
            for (int ks = 0; ks < 2; ++ks)
                a[i][ks] = *(const s8v*)&As[(64 * wm + 16 * i + el) * LSTR + ks * 32 + eh * 8];
        #pragma unroll
        for (int j = 0; j < 2; ++j)
            #pragma unroll
            for (int ks = 0; ks < 2; ++ks)
                b[j][ks] = *(const s8v*)&Bs[(32 * wn + 16 * j + el) * LSTR + ks * 32 + eh * 8];
        #pragma unroll
        for (int i = 0; i < 4; ++i)
            #pragma unroll
            for (int j = 0; j < 2; ++j)
                #pragma unroll
                for (int ks = 0; ks < 2; ++ks)
                    acc[i][j] = mfma16(a[i][ks], b[j][ks], acc[i][j]);
        __syncthreads();
    }
    #pragma unroll
    for (int i = 0; i < 4; ++i)
        #pragma unroll
        for (int j = 0; j < 2; ++j) {
            int n = n0 + 32 * wn + 16 * j + el;
            float bb = bp[n];
            #pragma unroll
            for (int r = 0; r < 4; ++r) {
                int m = m0 + 64 * wm + 16 * i + 4 * eh + r;
                out[(size_t)m * D_ + n] = acc[i][j][r] + bb;
            }
        }
}

// ---------------------------------------------------------------------------
extern "C" void kernel_launch(void* const* d_in, const int* in_sizes, int n_in,
                              void* d_out, int out_size, void* d_ws, size_t ws_size,
                              hipStream_t stream) {
    (void)in_sizes; (void)n_in; (void)out_size; (void)ws_size;
    const float* x  = (const float*)d_in[0];
    const float* Wq = (const float*)d_in[1];
    const float* bq = (const float*)d_in[2];
    const float* Wk = (const float*)d_in[3];
    const float* bk = (const float*)d_in[4];
    const float* Wv = (const float*)d_in[5];
    const float* bv = (const float*)d_in[6];
    const float* Wp = (const float*)d_in[7];
    const float* bp = (const float*)d_in[8];
    float* out = (float*)d_out;
    char* ws = (char*)d_ws;

    // workspace layout (bytes)
    unsigned short* xb    = (unsigned short*)(ws + 0);            // 16,777,216
    unsigned short* Wqkvb = (unsigned short*)(ws + 16777216);     //  6,291,456
    unsigned short* Wpb   = (unsigned short*)(ws + 23068672);     //  2,097,152
    unsigned short* qkvb  = (unsigned short*)(ws + 25165824);     // 50,331,648
    unsigned short* attb  = (unsigned short*)(ws + 75497472);     // 16,777,216  (end 92,274,688)

    cvt_f2b_kernel<<<2048, 256, 0, stream>>>(x, xb, (B_ * T_ * D_) / 4);
    cvt_f2b_kernel<<<1024, 256, 0, stream>>>(Wp, Wpb, (D_ * D_) / 4);
    cvt_wqkv<<<dim3(8, 48), 256, 0, stream>>>(Wq, Wk, Wv, Wqkvb);
    qkv_mm<<<dim3(64, 48), 256, 0, stream>>>(xb, Wqkvb, bq, bk, bv, qkvb);
    attn_mfma<<<dim3(T_ / 64, B_ * H_), 256, 0, stream>>>(qkvb, attb);
    proj_mm<<<dim3(64, 16), 256, 0, stream>>>(attb, Wpb, bp, out);
}

// Round 4
// 428.518 us; speedup vs baseline: 5.7752x; 1.1528x over previous
//
#include <hip/hip_runtime.h>
#include <math.h>

#define B_  4
#define T_  2048
#define D_  1024
#define H_  16
#define HD_ 64
#define CST2 0.1803368801111244f   // HD^-0.5 * log2(e)  (softmax in base-2)
#define LSTR 72   // LDS inner stride (bf16 units): multiple of 8 (b128-aligned), bank-rotating

typedef __attribute__((ext_vector_type(8))) short  s8v;
typedef __attribute__((ext_vector_type(4))) float  f4v;
typedef __attribute__((ext_vector_type(8))) unsigned short u8v;
typedef __attribute__((ext_vector_type(4))) unsigned short u4v;
typedef __attribute__((ext_vector_type(2))) unsigned short u2v;

static __device__ __forceinline__ unsigned short f2b(float f) {
    unsigned u = __builtin_bit_cast(unsigned, f);
    u = (u + 0x7fffu + ((u >> 16) & 1u)) >> 16;   // RNE
    return (unsigned short)u;
}
static __device__ __forceinline__ f4v mfma16(s8v a, s8v b, f4v c) {
    return __builtin_amdgcn_mfma_f32_16x16x32_bf16(a, b, c, 0, 0, 0);
}

// ---------------------------------------------------------------------------
// Prep 1: fp32 -> bf16 convert (x, Wp)
// ---------------------------------------------------------------------------
__global__ void cvt_f2b_kernel(const float* __restrict__ src,
                               unsigned short* __restrict__ dst, int n4) {
    int i = blockIdx.x * blockDim.x + threadIdx.x;
    int stride = gridDim.x * blockDim.x;
    for (; i < n4; i += stride) {
        float4 v = reinterpret_cast<const float4*>(src)[i];
        u4v o;
        o[0] = f2b(v.x); o[1] = f2b(v.y); o[2] = f2b(v.z); o[3] = f2b(v.w);
        reinterpret_cast<u4v*>(dst)[i] = o;
    }
}

// ---------------------------------------------------------------------------
// Prep 2: Wq/Wk/Wv [sel][h][k][e] fp32 -> Wb [sel*16+h][e][k] bf16 (transposed)
// ---------------------------------------------------------------------------
__global__ __launch_bounds__(256) void cvt_wqkv(
    const float* __restrict__ Wq, const float* __restrict__ Wk,
    const float* __restrict__ Wv, unsigned short* __restrict__ Wb) {
    const int tid = threadIdx.x;
    const int kblk = blockIdx.x;          // 0..7
    const int by = blockIdx.y;            // sel*16+h
    const int sel = by >> 4, h = by & 15;
    const float* W = (sel == 0 ? Wq : sel == 1 ? Wk : Wv) + (size_t)h * D_ * HD_ + (size_t)kblk * 128 * HD_;

    __shared__ unsigned short L[128 * 68];

    #pragma unroll
    for (int p = 0; p < 8; ++p) {
        int flat = p * 256 + tid;
        int r = flat >> 4, e4 = (flat & 15) * 4;
        float4 v = *(const float4*)&W[(size_t)r * HD_ + e4];
        L[r * 68 + e4 + 0] = f2b(v.x);
        L[r * 68 + e4 + 1] = f2b(v.y);
        L[r * 68 + e4 + 2] = f2b(v.z);
        L[r * 68 + e4 + 3] = f2b(v.w);
    }
    __syncthreads();
    #pragma unroll
    for (int p = 0; p < 8; ++p) {
        int flat = p * 256 + tid;
        int e = flat >> 5, rc = (flat & 31) * 4;
        u4v o;
        o[0] = L[(rc + 0) * 68 + e];
        o[1] = L[(rc + 1) * 68 + e];
        o[2] = L[(rc + 2) * 68 + e];
        o[3] = L[(rc + 3) * 68 + e];
        *(u4v*)&Wb[((size_t)by * HD_ + e) * D_ + kblk * 128 + rc] = o;
    }
}

// ---------------------------------------------------------------------------
// Kernel 1: fused QKV projection. BM=128, BN=128 (two heads), BK=64.
// 4 waves in 2x2; wave tile 64x64 (4x4 frags, 32 MFMA/k-step).
// ---------------------------------------------------------------------------
__global__ __launch_bounds__(256) void qkv_mm(
    const unsigned short* __restrict__ xb, const unsigned short* __restrict__ Wb,
    const float* __restrict__ bq, const float* __restrict__ bk_,
    const float* __restrict__ bv, unsigned short* __restrict__ qkvb) {
    const int tid = threadIdx.x;
    const int m0 = blockIdx.x * 128;
    const int by = blockIdx.y;            // sel*8 + hp  (0..23)
    const int sel = by >> 3, hp = by & 7;
    const float* bias = (sel == 0 ? bq : sel == 1 ? bk_ : bv);
    const unsigned short* Wt = Wb + (size_t)(sel * 16 + 2 * hp) * HD_ * D_;  // 128 e-rows x D

    __shared__ __align__(16) unsigned short As[128 * LSTR];
    __shared__ __align__(16) unsigned short Bs[128 * LSTR];

    const int w = tid >> 6, lane = tid & 63;
    const int el = lane & 15, eh = lane >> 4;
    const int wm = w >> 1, wn = w & 1;

    f4v acc[4][4];
    #pragma unroll
    for (int i = 0; i < 4; ++i)
        #pragma unroll
        for (int j = 0; j < 4; ++j) acc[i][j] = 0.f;

    for (int k0 = 0; k0 < D_; k0 += 64) {
        #pragma unroll
        for (int p = 0; p < 4; ++p) {
            int flat = p * 256 + tid;
            int row = flat >> 3, kc = (flat & 7) * 8;
            *(u8v*)&As[row * LSTR + kc] = *(const u8v*)&xb[(size_t)(m0 + row) * D_ + k0 + kc];
        }
        #pragma unroll
        for (int p = 0; p < 4; ++p) {
            int flat = p * 256 + tid;
            int n = flat >> 3, kc = (flat & 7) * 8;
            *(u8v*)&Bs[n * LSTR + kc] = *(const u8v*)&Wt[(size_t)n * D_ + k0 + kc];
        }
        __syncthreads();
        s8v a[4][2], b[4][2];
        #pragma unroll
        for (int i = 0; i < 4; ++i)
            #pragma unroll
            for (int ks = 0; ks < 2; ++ks)
                a[i][ks] = *(const s8v*)&As[(64 * wm + 16 * i + el) * LSTR + ks * 32 + eh * 8];
        #pragma unroll
        for (int j = 0; j < 4; ++j)
            #pragma unroll
            for (int ks = 0; ks < 2; ++ks)
                b[j][ks] = *(const s8v*)&Bs[(64 * wn + 16 * j + el) * LSTR + ks * 32 + eh * 8];
        __builtin_amdgcn_s_setprio(1);
        #pragma unroll
        for (int i = 0; i < 4; ++i)
            #pragma unroll
            for (int j = 0; j < 4; ++j)
                #pragma unroll
                for (int ks = 0; ks < 2; ++ks)
                    acc[i][j] = mfma16(a[i][ks], b[j][ks], acc[i][j]);
        __builtin_amdgcn_s_setprio(0);
        __syncthreads();
    }
    // store: n in [0,128): head h = 2*hp + (n>>6), e = n&63
    #pragma unroll
    for (int j = 0; j < 4; ++j) {
        int n = 64 * wn + 16 * j + el;
        int h = 2 * hp + (n >> 6);
        int e = n & 63;
        float bb = bias[h * HD_ + e];
        #pragma unroll
        for (int i = 0; i < 4; ++i)
            #pragma unroll
            for (int r = 0; r < 4; ++r) {
                int m = m0 + 64 * wm + 16 * i + 4 * eh + r;
                int bidx = m >> 11, t = m & (T_ - 1);
                size_t o = (((size_t)sel * B_ + bidx) * H_ + h) * (size_t)T_ * HD_ + (size_t)t * HD_ + e;
                qkvb[o] = f2b(acc[i][j][r] + bb);
            }
    }
}

// ---------------------------------------------------------------------------
// Kernel 2: causal flash attention. Block = (b,h, 128-row q-tile), 8 waves.
// Double-buffered K/V LDS, split reg-staging (T14), 1 barrier/tile, exp2 softmax.
// ---------------------------------------------------------------------------
__global__ __launch_bounds__(512, 4) void attn_mfma(
    const unsigned short* __restrict__ qkvb, unsigned short* __restrict__ attb) {
    const int tid = threadIdx.x;
    const int by = blockIdx.y;                  // b*H+h
    const int h = by & 15, b = by >> 4;
    const int qt = gridDim.x - 1 - blockIdx.x;  // heavy tiles first
    const int q0 = qt * 128;

    const size_t PL = (size_t)B_ * H_ * T_ * HD_;
    const unsigned short* Qp = qkvb + (size_t)by * T_ * HD_;
    const unsigned short* Kp = Qp + PL;
    const unsigned short* Vp = Qp + 2 * PL;

    const int w = tid >> 6, lane = tid & 63;
    const int el = lane & 15, eh = lane >> 4;
    const int qrbase = q0 + 16 * w;

    __shared__ __align__(16) unsigned short Ks[2][64 * LSTR];   // [kv][e]
    __shared__ __align__(16) unsigned short Vt[2][64 * LSTR];   // [e][kv]
    __shared__ __align__(16) unsigned short Pl[8][16 * LSTR];   // per-wave [qrow][kv]

    // Q A-frags, held in registers for the whole kernel
    s8v aq[2];
    #pragma unroll
    for (int ks = 0; ks < 2; ++ks)
        aq[ks] = *(const s8v*)&Qp[(size_t)(qrbase + el) * HD_ + ks * 32 + eh * 8];

    f4v o[4];
    #pragma unroll
    for (int j = 0; j < 4; ++j) o[j] = 0.f;
    float mrow[4], lrow[4];
    #pragma unroll
    for (int r = 0; r < 4; ++r) { mrow[r] = -INFINITY; lrow[r] = 0.f; }

    // staging registers
    u8v kreg;
    unsigned vreg[2][2];
    const int krow = tid >> 3, kcol = (tid & 7) * 8;   // K: one u8v per thread

    // ---- prologue: load + store tile 0
    {
        kreg = *(const u8v*)&Kp[(size_t)krow * HD_ + kcol];
        #pragma unroll
        for (int p = 0; p < 2; ++p) {
            int flat = p * 512 + tid;
            int kvp = flat >> 5, e2 = (flat & 31) * 2;
            u2v v0 = *(const u2v*)&Vp[(size_t)(2 * kvp) * HD_ + e2];
            u2v v1 = *(const u2v*)&Vp[(size_t)(2 * kvp + 1) * HD_ + e2];
            vreg[p][0] = (unsigned)v0[0] | ((unsigned)v1[0] << 16);
            vreg[p][1] = (unsigned)v0[1] | ((unsigned)v1[1] << 16);
        }
        *(u8v*)&Ks[0][krow * LSTR + kcol] = kreg;
        #pragma unroll
        for (int p = 0; p < 2; ++p) {
            int flat = p * 512 + tid;
            int kvp = flat >> 5, e2 = (flat & 31) * 2;
            *(unsigned*)&Vt[0][(e2 + 0) * LSTR + 2 * kvp] = vreg[p][0];
            *(unsigned*)&Vt[0][(e2 + 1) * LSTR + 2 * kvp] = vreg[p][1];
        }
    }

    const int ntiles = 2 * qt + 2;
    int cur = 0;
    for (int jt = 0; jt < ntiles; ++jt) {
        const int j0 = jt * 64;
        __syncthreads();   // buf[cur] ready; everyone done reading buf[cur^1]
        const bool more = (jt + 1 < ntiles);
        if (more) {        // issue next tile's global loads (latency hides under compute)
            const int jn = j0 + 64;
            kreg = *(const u8v*)&Kp[(size_t)(jn + krow) * HD_ + kcol];
            #pragma unroll
            for (int p = 0; p < 2; ++p) {
                int flat = p * 512 + tid;
                int kvp = flat >> 5, e2 = (flat & 31) * 2;
                u2v v0 = *(const u2v*)&Vp[(size_t)(jn + 2 * kvp) * HD_ + e2];
                u2v v1 = *(const u2v*)&Vp[(size_t)(jn + 2 * kvp + 1) * HD_ + e2];
                vreg[p][0] = (unsigned)v0[0] | ((unsigned)v1[0] << 16);
                vreg[p][1] = (unsigned)v0[1] | ((unsigned)v1[1] << 16);
            }
        }

        if (j0 <= qrbase + 15) {   // wave-uniform
            // S = Q K^T
            f4v s[4];
            #pragma unroll
            for (int f = 0; f < 4; ++f) s[f] = 0.f;
            __builtin_amdgcn_s_setprio(1);
            #pragma unroll
            for (int f = 0; f < 4; ++f)
                #pragma unroll
                for (int ks = 0; ks < 2; ++ks) {
                    s8v bk = *(const s8v*)&Ks[cur][(16 * f + el) * LSTR + ks * 32 + eh * 8];
                    s[f] = mfma16(aq[ks], bk, s[f]);
                }
            __builtin_amdgcn_s_setprio(0);

            // scale (+ causal mask only near the diagonal), base-2 domain
            float sv[4][4];
            if (j0 + 63 <= qrbase) {        // fully visible tile
                #pragma unroll
                for (int f = 0; f < 4; ++f)
                    #pragma unroll
                    for (int r = 0; r < 4; ++r) sv[f][r] = s[f][r] * CST2;
            } else {
                #pragma unroll
                for (int f = 0; f < 4; ++f)
                    #pragma unroll
                    for (int r = 0; r < 4; ++r) {
                        int row = qrbase + 4 * eh + r;
                        int col = j0 + 16 * f + el;
                        sv[f][r] = (col > row) ? -INFINITY : s[f][r] * CST2;
                    }
            }

            // online softmax (base-2), rows spread over 16 lanes
            float fac[4];
            #pragma unroll
            for (int r = 0; r < 4; ++r) {
                float pm = fmaxf(fmaxf(sv[0][r], sv[1][r]), fmaxf(sv[2][r], sv[3][r]));
                #pragma unroll
                for (int d = 1; d < 16; d <<= 1) pm = fmaxf(pm, __shfl_xor(pm, d));
                float mn = fmaxf(mrow[r], pm);
                fac[r] = __builtin_exp2f(mrow[r] - mn);
                mrow[r] = mn;
            }
            float rs[4] = {0.f, 0.f, 0.f, 0.f};
            #pragma unroll
            for (int f = 0; f < 4; ++f)
                #pragma unroll
                for (int r = 0; r < 4; ++r) {
                    float p = __builtin_exp2f(sv[f][r] - mrow[r]);
                    rs[r] += p;
                    Pl[w][(4 * eh + r) * LSTR + 16 * f + el] = f2b(p);
                }
            #pragma unroll
            for (int r = 0; r < 4; ++r) {
                #pragma unroll
                for (int d = 1; d < 16; d <<= 1) rs[r] += __shfl_xor(rs[r], d);
                lrow[r] = lrow[r] * fac[r] + rs[r];
            }
            #pragma unroll
            for (int j = 0; j < 4; ++j)
                #pragma unroll
                for (int r = 0; r < 4; ++r) o[j][r] *= fac[r];

            // O += P V
            s8v ap[2];
            #pragma unroll
            for (int ks = 0; ks < 2; ++ks)
                ap[ks] = *(const s8v*)&Pl[w][el * LSTR + ks * 32 + eh * 8];
            __builtin_amdgcn_s_setprio(1);
            #pragma unroll
            for (int j = 0; j < 4; ++j)
                #pragma unroll
                for (int ks = 0; ks < 2; ++ks) {
                    s8v bv_ = *(const s8v*)&Vt[cur][(16 * j + el) * LSTR + ks * 32 + eh * 8];
                    o[j] = mfma16(ap[ks], bv_, o[j]);
                }
            __builtin_amdgcn_s_setprio(0);
        }

        if (more) {   // write next tile into the other buffer (all waves past barrier)
            *(u8v*)&Ks[cur ^ 1][krow * LSTR + kcol] = kreg;
            #pragma unroll
            for (int p = 0; p < 2; ++p) {
                int flat = p * 512 + tid;
                int kvp = flat >> 5, e2 = (flat & 31) * 2;
                *(unsigned*)&Vt[cur ^ 1][(e2 + 0) * LSTR + 2 * kvp] = vreg[p][0];
                *(unsigned*)&Vt[cur ^ 1][(e2 + 1) * LSTR + 2 * kvp] = vreg[p][1];
            }
        }
        cur ^= 1;
    }

    // epilogue: normalize, write bf16 att[b][t][h*64+e]
    float inv[4];
    #pragma unroll
    for (int r = 0; r < 4; ++r) inv[r] = 1.0f / lrow[r];
    #pragma unroll
    for (int j = 0; j < 4; ++j)
        #pragma unroll
        for (int r = 0; r < 4; ++r) {
            int row = b * T_ + qrbase + 4 * eh + r;
            int col = h * HD_ + 16 * j + el;
            attb[(size_t)row * D_ + col] = f2b(o[j][r] * inv[r]);
        }
}

// ---------------------------------------------------------------------------
// Kernel 3: output projection. BM=128, BN=128. out = att * Wp^T + bp (fp32 out)
// ---------------------------------------------------------------------------
__global__ __launch_bounds__(256) void proj_mm(
    const unsigned short* __restrict__ ab, const unsigned short* __restrict__ Wpb,
    const float* __restrict__ bp, float* __restrict__ out) {
    const int tid = threadIdx.x;
    const int m0 = blockIdx.x * 128;
    const int n0 = blockIdx.y * 128;

    __shared__ __align__(16) unsigned short As[128 * LSTR];
    __shared__ __align__(16) unsigned short Bs[128 * LSTR];

    const int w = tid >> 6, lane = tid & 63;
    const int el = lane & 15, eh = lane >> 4;
    const int wm = w >> 1, wn = w & 1;

    f4v acc[4][4];
    #pragma unroll
    for (int i = 0; i < 4; ++i)
        #pragma unroll
        for (int j = 0; j < 4; ++j) acc[i][j] = 0.f;

    for (int k0 = 0; k0 < D_; k0 += 64) {
        #pragma unroll
        for (int p = 0; p < 4; ++p) {
            int flat = p * 256 + tid;
            int row = flat >> 3, kc = (flat & 7) * 8;
            *(u8v*)&As[row * LSTR + kc] = *(const u8v*)&ab[(size_t)(m0 + row) * D_ + k0 + kc];
        }
        #pragma unroll
        for (int p = 0; p < 4; ++p) {
            int flat = p * 256 + tid;
            int n = flat >> 3, kc = (flat & 7) * 8;
            *(u8v*)&Bs[n * LSTR + kc] = *(const u8v*)&Wpb[(size_t)(n0 + n) * D_ + k0 + kc];
        }
        __syncthreads();
        s8v a[4][2], b[4][2];
        #pragma unroll
        for (int i = 0; i < 4; ++i)
            #pragma unroll
            for (int ks = 0; ks < 2; ++ks)
                a[i][ks] = *(const s8v*)&As[(64 * wm + 16 * i + el) * LSTR + ks * 32 + eh * 8];
        #pragma unroll
        for (int j = 0; j < 4; ++j)
            #pragma unroll
            for (int ks = 0; ks < 2; ++ks)
                b[j][ks] = *(const s8v*)&Bs[(64 * wn + 16 * j + el) * LSTR + ks * 32 + eh * 8];
        __builtin_amdgcn_s_setprio(1);
        #pragma unroll
        for (int i = 0; i < 4; ++i)
            #pragma unroll
            for (int j = 0; j < 4; ++j)
                #pragma unroll
                for (int ks = 0; ks < 2; ++ks)
                    acc[i][j] = mfma16(a[i][ks], b[j][ks], acc[i][j]);
        __builtin_amdgcn_s_setprio(0);
        __syncthreads();
    }
    #pragma unroll
    for (int i = 0; i < 4; ++i)
        #pragma unroll
        for (int j = 0; j < 4; ++j) {
            int n = n0 + 64 * wn + 16 * j + el;
            float bb = bp[n];
            #pragma unroll
            for (int r = 0; r < 4; ++r) {
                int m = m0 + 64 * wm + 16 * i + 4 * eh + r;
                out[(size_t)m * D_ + n] = acc[i][j][r] + bb;
            }
        }
}

// ---------------------------------------------------------------------------
extern "C" void kernel_launch(void* const* d_in, const int* in_sizes, int n_in,
                              void* d_out, int out_size, void* d_ws, size_t ws_size,
                              hipStream_t stream) {
    (void)in_sizes; (void)n_in; (void)out_size; (void)ws_size;
    const float* x  = (const float*)d_in[0];
    const float* Wq = (const float*)d_in[1];
    const float* bq = (const float*)d_in[2];
    const float* Wk = (const float*)d_in[3];
    const float* bk = (const float*)d_in[4];
    const float* Wv = (const float*)d_in[5];
    const float* bv = (const float*)d_in[6];
    const float* Wp = (const float*)d_in[7];
    const float* bp = (const float*)d_in[8];
    float* out = (float*)d_out;
    char* ws = (char*)d_ws;

    unsigned short* xb    = (unsigned short*)(ws + 0);            // 16,777,216 B
    unsigned short* Wqkvb = (unsigned short*)(ws + 16777216);     //  6,291,456 B
    unsigned short* Wpb   = (unsigned short*)(ws + 23068672);     //  2,097,152 B
    unsigned short* qkvb  = (unsigned short*)(ws + 25165824);     // 50,331,648 B
    unsigned short* attb  = (unsigned short*)(ws + 75497472);     // 16,777,216 B

    cvt_f2b_kernel<<<2048, 256, 0, stream>>>(x, xb, (B_ * T_ * D_) / 4);
    cvt_f2b_kernel<<<1024, 256, 0, stream>>>(Wp, Wpb, (D_ * D_) / 4);
    cvt_wqkv<<<dim3(8, 48), 256, 0, stream>>>(Wq, Wk, Wv, Wqkvb);
    qkv_mm<<<dim3(64, 24), 256, 0, stream>>>(xb, Wqkvb, bq, bk, bv, qkvb);
    attn_mfma<<<dim3(T_ / 128, B_ * H_), 512, 0, stream>>>(qkvb, attb);
    proj_mm<<<dim3(64, 8), 256, 0, stream>>>(attb, Wpb, bp, out);
}

// Round 5
// 303.024 us; speedup vs baseline: 8.1670x; 1.4141x over previous
//
#include <hip/hip_runtime.h>
#include <math.h>

#define B_  4
#define T_  2048
#define D_  1024
#define H_  16
#define HD_ 64
#define CST2 0.1803368801111244f   // HD^-0.5 * log2(e): folded into Wq/bq at prep
#define LSTR 72
#define DEFER_THR 8.0f
#define PL_ ((size_t)B_ * H_ * T_ * HD_)

typedef __attribute__((ext_vector_type(8)))  short s8v;
typedef __attribute__((ext_vector_type(4)))  float f4v;
typedef __attribute__((ext_vector_type(16))) float f16v;
typedef __attribute__((ext_vector_type(8)))  unsigned short u8v;
typedef __attribute__((ext_vector_type(4)))  unsigned short u4v;
typedef __attribute__((ext_vector_type(4)))  unsigned int  u32x4;

static __device__ __forceinline__ unsigned short f2b(float f) {
    unsigned u = __builtin_bit_cast(unsigned, f);
    u = (u + 0x7fffu + ((u >> 16) & 1u)) >> 16;   // RNE
    return (unsigned short)u;
}
static __device__ __forceinline__ f4v mfma16(s8v a, s8v b, f4v c) {
    return __builtin_amdgcn_mfma_f32_16x16x32_bf16(a, b, c, 0, 0, 0);
}
static __device__ __forceinline__ f16v mfma32(s8v a, s8v b, f16v c) {
    return __builtin_amdgcn_mfma_f32_32x32x16_bf16(a, b, c, 0, 0, 0);
}

// ---------------------------------------------------------------------------
// Prep 1: fp32 -> bf16 convert (x, Wp)
// ---------------------------------------------------------------------------
__global__ void cvt_f2b_kernel(const float* __restrict__ src,
                               unsigned short* __restrict__ dst, int n4) {
    int i = blockIdx.x * blockDim.x + threadIdx.x;
    int stride = gridDim.x * blockDim.x;
    for (; i < n4; i += stride) {
        float4 v = reinterpret_cast<const float4*>(src)[i];
        u4v o;
        o[0] = f2b(v.x); o[1] = f2b(v.y); o[2] = f2b(v.z); o[3] = f2b(v.w);
        reinterpret_cast<u4v*>(dst)[i] = o;
    }
}

// ---------------------------------------------------------------------------
// Prep 2: Wq/Wk/Wv [sel][h][k][e] fp32 -> Wb [sel*16+h][e][k] bf16 (transposed)
// Wq additionally pre-scaled by CST2 (softmax scale folded into Q).
// ---------------------------------------------------------------------------
__global__ __launch_bounds__(256) void cvt_wqkv(
    const float* __restrict__ Wq, const float* __restrict__ Wk,
    const float* __restrict__ Wv, unsigned short* __restrict__ Wb) {
    const int tid = threadIdx.x;
    const int kblk = blockIdx.x;          // 0..7
    const int by = blockIdx.y;            // sel*16+h
    const int sel = by >> 4, h = by & 15;
    const float* W = (sel == 0 ? Wq : sel == 1 ? Wk : Wv) + (size_t)h * D_ * HD_ + (size_t)kblk * 128 * HD_;
    const float scl = (sel == 0) ? CST2 : 1.0f;

    __shared__ unsigned short L[128 * 68];

    #pragma unroll
    for (int p = 0; p < 8; ++p) {
        int flat = p * 256 + tid;
        int r = flat >> 4, e4 = (flat & 15) * 4;
        float4 v = *(const float4*)&W[(size_t)r * HD_ + e4];
        L[r * 68 + e4 + 0] = f2b(v.x * scl);
        L[r * 68 + e4 + 1] = f2b(v.y * scl);
        L[r * 68 + e4 + 2] = f2b(v.z * scl);
        L[r * 68 + e4 + 3] = f2b(v.w * scl);
    }
    __syncthreads();
    #pragma unroll
    for (int p = 0; p < 8; ++p) {
        int flat = p * 256 + tid;
        int e = flat >> 5, rc = (flat & 31) * 4;
        u4v o;
        o[0] = L[(rc + 0) * 68 + e];
        o[1] = L[(rc + 1) * 68 + e];
        o[2] = L[(rc + 2) * 68 + e];
        o[3] = L[(rc + 3) * 68 + e];
        *(u4v*)&Wb[((size_t)by * HD_ + e) * D_ + kblk * 128 + rc] = o;
    }
}

// ---------------------------------------------------------------------------
// Kernel 1: fused QKV projection. BM=128, BN=128 (two heads), BK=64.
// Q/K written [b,h,t,e]; V written TRANSPOSED [b,h,e,t] (for attn B-frags).
// ---------------------------------------------------------------------------
__global__ __launch_bounds__(256) void qkv_mm(
    const unsigned short* __restrict__ xb, const unsigned short* __restrict__ Wb,
    const float* __restrict__ bq, const float* __restrict__ bk_,
    const float* __restrict__ bv, unsigned short* __restrict__ qkvb) {
    const int tid = threadIdx.x;
    const int m0 = blockIdx.x * 128;
    const int by = blockIdx.y;            // sel*8 + hp
    const int sel = by >> 3, hp = by & 7;
    const float* bias = (sel == 0 ? bq : sel == 1 ? bk_ : bv);
    const float bscale = (sel == 0) ? CST2 : 1.0f;
    const unsigned short* Wt = Wb + (size_t)(sel * 16 + 2 * hp) * HD_ * D_;

    __shared__ __align__(16) unsigned short As[128 * LSTR];
    __shared__ __align__(16) unsigned short Bs[128 * LSTR];

    const int w = tid >> 6, lane = tid & 63;
    const int el = lane & 15, eh = lane >> 4;
    const int wm = w >> 1, wn = w & 1;

    f4v acc[4][4];
    #pragma unroll
    for (int i = 0; i < 4; ++i)
        #pragma unroll
        for (int j = 0; j < 4; ++j) acc[i][j] = 0.f;

    for (int k0 = 0; k0 < D_; k0 += 64) {
        #pragma unroll
        for (int p = 0; p < 4; ++p) {
            int flat = p * 256 + tid;
            int row = flat >> 3, kc = (flat & 7) * 8;
            *(u8v*)&As[row * LSTR + kc] = *(const u8v*)&xb[(size_t)(m0 + row) * D_ + k0 + kc];
        }
        #pragma unroll
        for (int p = 0; p < 4; ++p) {
            int flat = p * 256 + tid;
            int n = flat >> 3, kc = (flat & 7) * 8;
            *(u8v*)&Bs[n * LSTR + kc] = *(const u8v*)&Wt[(size_t)n * D_ + k0 + kc];
        }
        __syncthreads();
        s8v a[4][2], b[4][2];
        #pragma unroll
        for (int i = 0; i < 4; ++i)
            #pragma unroll
            for (int ks = 0; ks < 2; ++ks)
                a[i][ks] = *(const s8v*)&As[(64 * wm + 16 * i + el) * LSTR + ks * 32 + eh * 8];
        #pragma unroll
        for (int j = 0; j < 4; ++j)
            #pragma unroll
            for (int ks = 0; ks < 2; ++ks)
                b[j][ks] = *(const s8v*)&Bs[(64 * wn + 16 * j + el) * LSTR + ks * 32 + eh * 8];
        __builtin_amdgcn_s_setprio(1);
        #pragma unroll
        for (int i = 0; i < 4; ++i)
            #pragma unroll
            for (int j = 0; j < 4; ++j)
                #pragma unroll
                for (int ks = 0; ks < 2; ++ks)
                    acc[i][j] = mfma16(a[i][ks], b[j][ks], acc[i][j]);
        __builtin_amdgcn_s_setprio(0);
        __syncthreads();
    }

    if (sel == 2) {
        // V: transposed store [b][h][e][t], u4v of 4 consecutive t
        #pragma unroll
        for (int j = 0; j < 4; ++j) {
            int n = 64 * wn + 16 * j + el;
            int h2 = 2 * hp + (n >> 6);
            int e = n & 63;
            float bb = bias[h2 * HD_ + e];
            #pragma unroll
            for (int i = 0; i < 4; ++i) {
                int m = m0 + 64 * wm + 16 * i + 4 * eh;
                int bidx = m >> 11, t = m & (T_ - 1);
                u4v pk4;
                #pragma unroll
                for (int r = 0; r < 4; ++r) pk4[r] = f2b(acc[i][j][r] + bb);
                *(u4v*)&qkvb[2 * PL_ + ((size_t)(bidx * H_ + h2) * HD_ + e) * T_ + t] = pk4;
            }
        }
    } else {
        #pragma unroll
        for (int j = 0; j < 4; ++j) {
            int n = 64 * wn + 16 * j + el;
            int h2 = 2 * hp + (n >> 6);
            int e = n & 63;
            float bb = bias[h2 * HD_ + e] * bscale;
            #pragma unroll
            for (int i = 0; i < 4; ++i)
                #pragma unroll
                for (int r = 0; r < 4; ++r) {
                    int m = m0 + 64 * wm + 16 * i + 4 * eh + r;
                    int bidx = m >> 11, t = m & (T_ - 1);
                    size_t o = (((size_t)sel * B_ + bidx) * H_ + h2) * (size_t)T_ * HD_ + (size_t)t * HD_ + e;
                    qkvb[o] = f2b(acc[i][j][r] + bb);
                }
        }
    }
}

// ---------------------------------------------------------------------------
// Kernel 2: causal flash attention, swapped-QK^T in-register softmax.
// Block = (b,h, 256-row q-tile), 8 waves x 32 q-rows, 32x32x16 MFMA.
// S^T = mfma(K,Q): lane (el,hi) holds P[q=el][kv slice] in regs.
// P -> PV A-frags via v_cvt_pk_bf16_f32 + v_permlane32_swap_b32 (no LDS).
// Defer-max (THR=8): O-rescale broadcast only when max grows.
// ---------------------------------------------------------------------------
__global__ __launch_bounds__(512, 4) void attn_mfma(
    const unsigned short* __restrict__ qkvb, unsigned short* __restrict__ attb) {
    const int tid = threadIdx.x;
    const int by = blockIdx.y;                  // b*H+h
    const int h = by & 15, b = by >> 4;
    const int qt = gridDim.x - 1 - blockIdx.x;  // heavy tiles first
    const int q0 = qt * 256;

    const unsigned short* Qp  = qkvb + (size_t)by * T_ * HD_;
    const unsigned short* Kp  = Qp + PL_;
    const unsigned short* Vtp = qkvb + 2 * PL_ + (size_t)by * HD_ * T_;  // [e][t]

    const int w = tid >> 6, lane = tid & 63;
    const int el = lane & 31, hi = lane >> 5;
    const int qr = q0 + 32 * w;                 // wave's first q-row

    __shared__ __align__(16) unsigned short Ks[2][64 * LSTR];   // [kv][e]
    __shared__ __align__(16) unsigned short Vt[2][64 * LSTR];   // [e][kv]

    // Q B-frags: B[col=q=el][k=e=16*st+8*hi+j]  (Q pre-scaled by CST2)
    s8v aq[4];
    #pragma unroll
    for (int st = 0; st < 4; ++st)
        aq[st] = *(const s8v*)&Qp[(size_t)(qr + el) * HD_ + 16 * st + 8 * hi];

    f16v o0 = 0.f, o1 = 0.f;       // O[q=reg-row][e=el], e=el+32
    float mrow = -INFINITY, lrow = 0.f;

    // staging (1 u8v each per thread)
    const int krow = tid >> 3, kcol8 = (tid & 7) * 8;
    u8v kreg, vreg;
    kreg = *(const u8v*)&Kp[(size_t)krow * HD_ + kcol8];
    vreg = *(const u8v*)&Vtp[(size_t)krow * T_ + kcol8];
    *(u8v*)&Ks[0][krow * LSTR + kcol8] = kreg;
    *(u8v*)&Vt[0][krow * LSTR + kcol8] = vreg;

    const int ntiles = 4 * (qt + 1);
    int cur = 0;
    for (int jt = 0; jt < ntiles; ++jt) {
        const int j0 = jt * 64;
        __syncthreads();
        const bool more = (jt + 1 < ntiles);
        if (more) {
            const int jn = j0 + 64;
            kreg = *(const u8v*)&Kp[(size_t)(jn + krow) * HD_ + kcol8];
            vreg = *(const u8v*)&Vtp[(size_t)krow * T_ + jn + kcol8];
        }

        if (j0 <= qr + 31) {   // wave-uniform
            // S^T = K * Q^T : D[row=kv][col=q]
            f16v s0 = 0.f, s1 = 0.f;
            __builtin_amdgcn_s_setprio(1);
            #pragma unroll
            for (int st = 0; st < 4; ++st) {
                s8v ka = *(const s8v*)&Ks[cur][(el) * LSTR + 16 * st + 8 * hi];
                s0 = mfma32(ka, aq[st], s0);
            }
            #pragma unroll
            for (int st = 0; st < 4; ++st) {
                s8v ka = *(const s8v*)&Ks[cur][(32 + el) * LSTR + 16 * st + 8 * hi];
                s1 = mfma32(ka, aq[st], s1);
            }
            __builtin_amdgcn_s_setprio(0);

            // causal mask (diagonal tile only); lane's q-col = qr+el, kv per reg
            if (j0 + 63 > qr) {
                const int q = qr + el;
                #pragma unroll
                for (int r = 0; r < 16; ++r) {
                    int kv0 = j0 + (r & 3) + 8 * (r >> 2) + 4 * hi;
                    if (kv0 > q)      s0[r] = -INFINITY;
                    if (kv0 + 32 > q) s1[r] = -INFINITY;
                }
            }

            // row max: in-lane chain + one cross-half merge
            float pm = s0[0];
            #pragma unroll
            for (int r = 1; r < 16; ++r) pm = fmaxf(pm, s0[r]);
            #pragma unroll
            for (int r = 0; r < 16; ++r) pm = fmaxf(pm, s1[r]);
            pm = fmaxf(pm, __shfl_xor(pm, 32));

            // defer-max: rescale only if max grew by > THR
            if (__any(pm > mrow + DEFER_THR)) {
                float mnew = fmaxf(mrow, pm);
                float fac  = __builtin_exp2f(mrow - mnew);
                mrow = mnew;
                lrow *= fac;
                #pragma unroll
                for (int r = 0; r < 16; ++r) {
                    int qidx = (r & 3) + 8 * (r >> 2) + 4 * hi;
                    float f = __shfl(fac, qidx);
                    o0[r] *= f; o1[r] *= f;
                }
            }

            // fused exp -> pack -> permlane -> PV, one 16-kv step at a time
            float rsum = 0.f;
            #define PV_STEP(SREG, BASE, ST)                                              \
            {                                                                            \
                float p0 = __builtin_exp2f(SREG[BASE + 0] - mrow);                       \
                float p1 = __builtin_exp2f(SREG[BASE + 1] - mrow);                       \
                float p2 = __builtin_exp2f(SREG[BASE + 2] - mrow);                       \
                float p3 = __builtin_exp2f(SREG[BASE + 3] - mrow);                       \
                float p4 = __builtin_exp2f(SREG[BASE + 4] - mrow);                       \
                float p5 = __builtin_exp2f(SREG[BASE + 5] - mrow);                       \
                float p6 = __builtin_exp2f(SREG[BASE + 6] - mrow);                       \
                float p7 = __builtin_exp2f(SREG[BASE + 7] - mrow);                       \
                rsum += ((p0 + p1) + (p2 + p3)) + ((p4 + p5) + (p6 + p7));               \
                unsigned a0, a1, a2, a3;                                                 \
                asm("v_cvt_pk_bf16_f32 %0, %1, %2" : "=v"(a0) : "v"(p0), "v"(p1));       \
                asm("v_cvt_pk_bf16_f32 %0, %1, %2" : "=v"(a1) : "v"(p2), "v"(p3));       \
                asm("v_cvt_pk_bf16_f32 %0, %1, %2" : "=v"(a2) : "v"(p4), "v"(p5));       \
                asm("v_cvt_pk_bf16_f32 %0, %1, %2" : "=v"(a3) : "v"(p6), "v"(p7));       \
                asm("v_permlane32_swap_b32 %0, %1" : "+v"(a0), "+v"(a2));                \
                asm("v_permlane32_swap_b32 %0, %1" : "+v"(a1), "+v"(a3));                \
                s8v pa = __builtin_bit_cast(s8v, (u32x4){a0, a1, a2, a3});               \
                s8v vb0 = *(const s8v*)&Vt[cur][(el) * LSTR + 16 * ST + 8 * hi];         \
                s8v vb1 = *(const s8v*)&Vt[cur][(32 + el) * LSTR + 16 * ST + 8 * hi];    \
                o0 = mfma32(pa, vb0, o0);                                                \
                o1 = mfma32(pa, vb1, o1);                                                \
            }
            PV_STEP(s0, 0, 0)
            PV_STEP(s0, 8, 1)
            PV_STEP(s1, 0, 2)
            PV_STEP(s1, 8, 3)
            #undef PV_STEP

            rsum += __shfl_xor(rsum, 32);
            lrow += rsum;
        }

        if (more) {
            *(u8v*)&Ks[cur ^ 1][krow * LSTR + kcol8] = kreg;
            *(u8v*)&Vt[cur ^ 1][krow * LSTR + kcol8] = vreg;
        }
        cur ^= 1;
    }

    // epilogue: normalize + store att[b][q][h*64+e]
    float linv = 1.0f / lrow;
    #pragma unroll
    for (int r = 0; r < 16; ++r) {
        int qidx = (r & 3) + 8 * (r >> 2) + 4 * hi;
        float lv = __shfl(linv, qidx);
        size_t row = (size_t)(b * T_ + qr + qidx) * D_ + h * HD_;
        attb[row + el]      = f2b(o0[r] * lv);
        attb[row + 32 + el] = f2b(o1[r] * lv);
    }
}

// ---------------------------------------------------------------------------
// Kernel 3: output projection. BM=128, BN=128. out = att * Wp^T + bp (fp32)
// ---------------------------------------------------------------------------
__global__ __launch_bounds__(256) void proj_mm(
    const unsigned short* __restrict__ ab, const unsigned short* __restrict__ Wpb,
    const float* __restrict__ bp, float* __restrict__ out) {
    const int tid = threadIdx.x;
    const int m0 = blockIdx.x * 128;
    const int n0 = blockIdx.y * 128;

    __shared__ __align__(16) unsigned short As[128 * LSTR];
    __shared__ __align__(16) unsigned short Bs[128 * LSTR];

    const int w = tid >> 6, lane = tid & 63;
    const int el = lane & 15, eh = lane >> 4;
    const int wm = w >> 1, wn = w & 1;

    f4v acc[4][4];
    #pragma unroll
    for (int i = 0; i < 4; ++i)
        #pragma unroll
        for (int j = 0; j < 4; ++j) acc[i][j] = 0.f;

    for (int k0 = 0; k0 < D_; k0 += 64) {
        #pragma unroll
        for (int p = 0; p < 4; ++p) {
            int flat = p * 256 + tid;
            int row = flat >> 3, kc = (flat & 7) * 8;
            *(u8v*)&As[row * LSTR + kc] = *(const u8v*)&ab[(size_t)(m0 + row) * D_ + k0 + kc];
        }
        #pragma unroll
        for (int p = 0; p < 4; ++p) {
            int flat = p * 256 + tid;
            int n = flat >> 3, kc = (flat & 7) * 8;
            *(u8v*)&Bs[n * LSTR + kc] = *(const u8v*)&Wpb[(size_t)(n0 + n) * D_ + k0 + kc];
        }
        __syncthreads();
        s8v a[4][2], b[4][2];
        #pragma unroll
        for (int i = 0; i < 4; ++i)
            #pragma unroll
            for (int ks = 0; ks < 2; ++ks)
                a[i][ks] = *(const s8v*)&As[(64 * wm + 16 * i + el) * LSTR + ks * 32 + eh * 8];
        #pragma unroll
        for (int j = 0; j < 4; ++j)
            #pragma unroll
            for (int ks = 0; ks < 2; ++ks)
                b[j][ks] = *(const s8v*)&Bs[(64 * wn + 16 * j + el) * LSTR + ks * 32 + eh * 8];
        __builtin_amdgcn_s_setprio(1);
        #pragma unroll
        for (int i = 0; i < 4; ++i)
            #pragma unroll
            for (int j = 0; j < 4; ++j)
                #pragma unroll
                for (int ks = 0; ks < 2; ++ks)
                    acc[i][j] = mfma16(a[i][ks], b[j][ks], acc[i][j]);
        __builtin_amdgcn_s_setprio(0);
        __syncthreads();
    }
    #pragma unroll
    for (int i = 0; i < 4; ++i)
        #pragma unroll
        for (int j = 0; j < 4; ++j) {
            int n = n0 + 64 * wn + 16 * j + el;
            float bb = bp[n];
            #pragma unroll
            for (int r = 0; r < 4; ++r) {
                int m = m0 + 64 * wm + 16 * i + 4 * eh + r;
                out[(size_t)m * D_ + n] = acc[i][j][r] + bb;
            }
        }
}

// ---------------------------------------------------------------------------
extern "C" void kernel_launch(void* const* d_in, const int* in_sizes, int n_in,
                              void* d_out, int out_size, void* d_ws, size_t ws_size,
                              hipStream_t stream) {
    (void)in_sizes; (void)n_in; (void)out_size; (void)ws_size;
    const float* x  = (const float*)d_in[0];
    const float* Wq = (const float*)d_in[1];
    const float* bq = (const float*)d_in[2];
    const float* Wk = (const float*)d_in[3];
    const float* bk = (const float*)d_in[4];
    const float* Wv = (const float*)d_in[5];
    const float* bv = (const float*)d_in[6];
    const float* Wp = (const float*)d_in[7];
    const float* bp = (const float*)d_in[8];
    float* out = (float*)d_out;
    char* ws = (char*)d_ws;

    unsigned short* xb    = (unsigned short*)(ws + 0);            // 16,777,216 B
    unsigned short* Wqkvb = (unsigned short*)(ws + 16777216);     //  6,291,456 B
    unsigned short* Wpb   = (unsigned short*)(ws + 23068672);     //  2,097,152 B
    unsigned short* qkvb  = (unsigned short*)(ws + 25165824);     // 50,331,648 B
    unsigned short* attb  = (unsigned short*)(ws + 75497472);     // 16,777,216 B

    cvt_f2b_kernel<<<2048, 256, 0, stream>>>(x, xb, (B_ * T_ * D_) / 4);
    cvt_f2b_kernel<<<1024, 256, 0, stream>>>(Wp, Wpb, (D_ * D_) / 4);
    cvt_wqkv<<<dim3(8, 48), 256, 0, stream>>>(Wq, Wk, Wv, Wqkvb);
    qkv_mm<<<dim3(64, 24), 256, 0, stream>>>(xb, Wqkvb, bq, bk, bv, qkvb);
    attn_mfma<<<dim3(T_ / 256, B_ * H_), 512, 0, stream>>>(qkvb, attb);
    proj_mm<<<dim3(64, 8), 256, 0, stream>>>(attb, Wpb, bp, out);
}